// Round 1
// baseline (876.481 us; speedup 1.0000x reference)
//
#include <hip/hip_runtime.h>

#define H 256
#define W 512
#define BATCH 4
#define HW (H*W)
#define NPIX (BATCH*HW)
#define SPAN 11
#define KK 23
#define NBINS (KK*KK)   // 529

#define LOG2E 1.4426950408889634f
#define CEXP  (-0.7213475204444817f)   // -0.5*log2(e)
#define CRGB  (CEXP*100.0f)            // 1/SIG_RGB^2 = 100
#define CDEP  (CEXP*25.0f)             // 1/SIG_DEPTH^2 = 25
#define CIND  (CEXP/36.0f)             // 1/SIG_XY^2 = 1/36

struct Pix { float r,g,b,d,y0,y1,y2,m; };

__device__ __forceinline__ void loadpix(const float* __restrict__ imgb,
                                        const float* __restrict__ depb,
                                        const float4* __restrict__ ydb,
                                        int row, int jn, bool jok, Pix& p) {
  bool ok = jok && ((unsigned)row < (unsigned)H);
  p.r=0.f; p.g=0.f; p.b=0.f; p.d=0.f; p.y0=0.f; p.y1=0.f; p.y2=0.f; p.m=0.f;
  if (ok) {
    int q = row*W + jn;
    p.r = imgb[q]; p.g = imgb[HW+q]; p.b = imgb[2*HW+q];
    p.d = depb[q];
    float4 y = ydb[q];
    p.y0=y.x; p.y1=y.y; p.y2=y.z; p.m=y.w;
  }
}

// ---------------- Kernel A: softmax precompute + CE partial sums ----------------
__global__ __launch_bounds__(256) void pre_kernel(const float* __restrict__ logit,
                                                  const int* __restrict__ target,
                                                  const float* __restrict__ dst,
                                                  float4* __restrict__ yd,
                                                  float* __restrict__ ce) {
  int p = blockIdx.x*256 + threadIdx.x;
  int b = p / HW, q = p - b*HW;
  const float* lg = logit + (size_t)b*3*HW + q;
  float l0 = lg[0], l1 = lg[HW], l2 = lg[2*HW];
  float mx = fmaxf(l0, fmaxf(l1, l2));
  float e0 = __builtin_amdgcn_exp2f((l0-mx)*LOG2E);
  float e1 = __builtin_amdgcn_exp2f((l1-mx)*LOG2E);
  float e2 = __builtin_amdgcn_exp2f((l2-mx)*LOG2E);
  float S = e0+e1+e2;
  float inv = 1.0f / S;
  float d = dst[p];
  yd[p] = make_float4(e0*inv, e1*inv, e2*inv, d);

  int t = target[p];
  float lt = (t==0) ? l0 : ((t==1) ? l1 : l2);
  float lce = mx + __logf(S) - lt;   // -log_softmax at target class
  float v0 = lce*d;
  float v1 = lce - v0;               // lce*(1-d)
  float v2 = d;
  #pragma unroll
  for (int s=1; s<64; s<<=1) {
    v0 += __shfl_xor(v0,s,64);
    v1 += __shfl_xor(v1,s,64);
    v2 += __shfl_xor(v2,s,64);
  }
  if ((threadIdx.x & 63)==0) {
    unsafeAtomicAdd(&ce[0], v0);
    unsafeAtomicAdd(&ce[1], v1);
    unsafeAtomicAdd(&ce[2], v2);
  }
}

// ---------------- Kernel B: CRF pair loop ----------------
// grid (W/256, H/4, B), block 256. Thread owns 4 center rows (i0..i0+3) at col j.
// Inner loop slides dx=+11..-11 with a 4-row register window of neighbor pixels.
__global__ __launch_bounds__(256) void crf_kernel(const float* __restrict__ image,
                                                  const float* __restrict__ depth,
                                                  const float4* __restrict__ yd,
                                                  float* __restrict__ g_bins) {
  __shared__ float bins[4][2*NBINS];
  int tx = threadIdx.x;
  int lane = tx & 63, wv = tx >> 6;
  for (int s = tx; s < 4*2*NBINS; s += 256) (&bins[0][0])[s] = 0.f;
  __syncthreads();

  int b  = blockIdx.z;
  int i0 = blockIdx.y * 4;
  int j  = blockIdx.x * 256 + tx;
  const float*  imgb = image + (size_t)b*3*HW;
  const float*  depb = depth + (size_t)b*HW;
  const float4* ydb  = yd    + (size_t)b*HW;

  float cr[4],cg[4],cb[4],cd[4],cy0[4],cy1[4],cy2[4];
  #pragma unroll
  for (int k=0;k<4;k++){
    int q = (i0+k)*W + j;
    cr[k]=imgb[q]; cg[k]=imgb[HW+q]; cb[k]=imgb[2*HW+q]; cd[k]=depb[q];
    float4 y = ydb[q]; cy0[k]=y.x; cy1[k]=y.y; cy2[k]=y.z;
  }

  #pragma unroll 1
  for (int dyi=0; dyi<22; ++dyi) {
    int dy = (dyi < 11) ? (dyi-11) : (dyi-10);
    int jn = j - dy;
    bool jok = ((unsigned)jn < (unsigned)W);
    float ldy = CIND * (float)(dy*dy);
    Pix w0,w1,w2,w3;
    loadpix(imgb,depb,ydb, i0-11, jn, jok, w0);
    loadpix(imgb,depb,ydb, i0-10, jn, jok, w1);
    loadpix(imgb,depb,ydb, i0-9 , jn, jok, w2);
    loadpix(imgb,depb,ydb, i0-8 , jn, jok, w3);

    #pragma unroll 1
    for (int dxs=0; dxs<23; ++dxs) {
      int dx = 11 - dxs;
      if (dxs != 11) {
        float lind = fmaf((float)(dx*dx), CIND, ldy);
        float num = 0.f, den = 0.f;
#define PAIR(k, wk) { \
        float dr = wk.r - cr[k], dg = wk.g - cg[k], db = wk.b - cb[k]; \
        float dd = wk.d - cd[k]; \
        float rgbsq = fmaf(dr,dr, fmaf(dg,dg, db*db)); \
        float a1 = fmaf(rgbsq, CRGB, lind); \
        float a2 = (dd*dd) * CDEP; \
        float kv = __builtin_amdgcn_exp2f(a1) + __builtin_amdgcn_exp2f(a2); \
        float dot = fmaf(wk.y0, cy0[k], fmaf(wk.y1, cy1[k], wk.y2*cy2[k])); \
        num = fmaf(kv * (1.0f - dot), wk.m, num); \
        den += wk.m; }
        PAIR(0, w0) PAIR(1, w1) PAIR(2, w2) PAIR(3, w3)
#undef PAIR
        #pragma unroll
        for (int s=1; s<64; s<<=1) {
          num += __shfl_xor(num, s, 64);
          den += __shfl_xor(den, s, 64);
        }
        if (lane == 0) {
          int od = (dx+SPAN)*KK + (dy+SPAN);
          bins[wv][od]       += num;
          bins[wv][NBINS+od] += den;
        }
      }
      if (dxs < 22) {
        w0 = w1; w1 = w2; w2 = w3;
        loadpix(imgb,depb,ydb, i0 + dxs - 7, jn, jok, w3);  // row i0+3-(dx-1)
      }
    }
  }
  __syncthreads();
  for (int s = tx; s < 2*NBINS; s += 256) {
    float v = bins[0][s]+bins[1][s]+bins[2][s]+bins[3][s];
    if (v != 0.f) unsafeAtomicAdd(&g_bins[s], v);
  }
}

// ---------------- Kernel C: finalize ----------------
__global__ __launch_bounds__(256) void fin_kernel(const float* __restrict__ bins,
                                                  const float* __restrict__ ce,
                                                  float* __restrict__ out) {
  int t = threadIdx.x;
  float esum = 0.f;
  for (int od = t; od < NBINS; od += 256) {
    int dxp = od / KK, dyp = od - dxp*KK;
    if (dxp != SPAN && dyp != SPAN) {
      esum += bins[od] / bins[NBINS+od];
    }
  }
  #pragma unroll
  for (int s=1; s<64; s<<=1) esum += __shfl_xor(esum, s, 64);
  __shared__ float r[4];
  if ((t&63)==0) r[t>>6] = esum;
  __syncthreads();
  if (t==0) {
    float tot = (r[0]+r[1]+r[2]+r[3]) / (float)NBINS;
    const float invN = 1.0f/(float)NPIX;
    float l1 = ce[0]*invN, l2 = ce[1]*invN, cnt = ce[2]*invN;
    out[0] = l1*(1.0f-cnt) + l2*cnt;
    out[1] = tot;
  }
}

extern "C" void kernel_launch(void* const* d_in, const int* in_sizes, int n_in,
                              void* d_out, int out_size, void* d_ws, size_t ws_size,
                              hipStream_t stream) {
  const float* logit  = (const float*)d_in[0];
  const int*   target = (const int*)  d_in[1];
  const float* image  = (const float*)d_in[2];
  const float* depth  = (const float*)d_in[3];
  const float* dstm   = (const float*)d_in[4];
  // d_in[5] source_map: unused by reference
  float* out = (float*)d_out;

  char* ws = (char*)d_ws;
  float4* yd   = (float4*)ws;                       // NPIX * 16 B = 8 MB
  float*  bins = (float*)(ws + (size_t)NPIX*16);    // 2*NBINS floats
  float*  ce   = bins + 2*NBINS;                    // 3 floats

  hipMemsetAsync(bins, 0, (2*NBINS + 3)*sizeof(float), stream);
  pre_kernel<<<NPIX/256, 256, 0, stream>>>(logit, target, dstm, yd, ce);
  crf_kernel<<<dim3(W/256, H/4, BATCH), 256, 0, stream>>>(image, depth, yd, bins);
  fin_kernel<<<1, 256, 0, stream>>>(bins, ce, out);
}

// Round 2
// 458.914 us; speedup vs baseline: 1.9099x; 1.9099x over previous
//
#include <hip/hip_runtime.h>

#define H 256
#define W 512
#define HW (H*W)
#define NPIXF 524288.0f
#define SPAN 11
#define KK 23
#define NBINS (KK*KK)   // 529

#define LOG2E 1.4426950408889634f
#define CEXP  (-0.7213475204444817f)   // -0.5*log2(e)
#define CRGB  (CEXP*100.0f)            // 1/SIG_RGB^2
#define CDEP  (CEXP*25.0f)             // 1/SIG_DEPTH^2
#define CIND  (CEXP/36.0f)             // 1/SIG_XY^2

// tile geometry: center 32 cols x 16 rows per block, halo +11 rows below, +-11 cols
#define TX 32
#define TYR 16
#define TROWS 27          // TYR + 11
#define TCOLS 54          // TX + 22
#define TPIX (TROWS*TCOLS) // 1458

struct Pix { float4 a; float4 b; };  // a = (r,g,b,depth), b = (y0,y1,y2,m)

// ---------------- den_kernel: column running sums of dst (summed over batch) ----------------
// A[ridx][j]: ridx 0..10 -> prefix at row i=ridx ; ridx 11..22 -> prefix at row i=ridx+233 (244..255)
__global__ __launch_bounds__(64) void den_kernel(const float* __restrict__ dst,
                                                 float* __restrict__ A) {
  int j = blockIdx.x*64 + threadIdx.x;   // 8 blocks x 64 = 512 columns
  float s = 0.f;
  for (int i = 0; i < H; ++i) {
    int q = i*W + j;
    s += dst[q] + dst[HW+q] + dst[2*HW+q] + dst[3*HW+q];
    if (i <= 10)       A[i*W + j] = s;
    else if (i >= 244) A[(i-233)*W + j] = s;
  }
}

// ---------------- crf_kernel: LDS-tiled pair loop + fused softmax/CE ----------------
__global__ __launch_bounds__(256, 3) void crf_kernel(
    const float* __restrict__ logit, const int* __restrict__ target,
    const float* __restrict__ image, const float* __restrict__ depth,
    const float* __restrict__ dst,
    float* __restrict__ g_bins, float* __restrict__ g_ce) {
  __shared__ float4 tileA[TPIX];
  __shared__ float4 tileB[TPIX];
  __shared__ float  binsS[NBINS];
  __shared__ float  redS[8];

  int tx = threadIdx.x;
  int bz = blockIdx.z;
  int i0 = blockIdx.y * TYR;
  int j0 = blockIdx.x * TX;

  const float* lg0 = logit + (size_t)bz*3*HW;
  const float* lg1 = lg0 + HW;
  const float* lg2 = lg0 + 2*HW;
  const float* im0 = image + (size_t)bz*3*HW;
  const float* im1 = im0 + HW;
  const float* im2 = im0 + 2*HW;
  const float* dep = depth + (size_t)bz*HW;
  const float* dsb = dst   + (size_t)bz*HW;
  const int*   tgb = target + (size_t)bz*HW;

  for (int s = tx; s < NBINS; s += 256) binsS[s] = 0.f;

  // --- staging: global -> LDS, with fused softmax; fused CE on center pixels ---
  float v0 = 0.f, v1 = 0.f;
  for (int s = tx; s < TPIX; s += 256) {
    int r = s / TCOLS, c = s - r*TCOLS;
    int gi = i0 + r, gj = j0 - 11 + c;
    float4 va, vb;
    if (gi < H && (unsigned)gj < (unsigned)W) {
      int q = gi*W + gj;
      float l0 = lg0[q], l1 = lg1[q], l2 = lg2[q];
      float mx = fmaxf(l0, fmaxf(l1, l2));
      float e0 = __builtin_amdgcn_exp2f((l0-mx)*LOG2E);
      float e1 = __builtin_amdgcn_exp2f((l1-mx)*LOG2E);
      float e2 = __builtin_amdgcn_exp2f((l2-mx)*LOG2E);
      float S = e0+e1+e2;
      float inv = 1.0f/S;
      float m = dsb[q];
      va = make_float4(im0[q], im1[q], im2[q], dep[q]);
      vb = make_float4(e0*inv, e1*inv, e2*inv, m);
      if (r < TYR && c >= 11 && c < 11+TX) {   // center pixel: CE terms
        int t = tgb[q];
        float lt = (t==0) ? l0 : ((t==1) ? l1 : l2);
        float lce = mx + __logf(S) - lt;
        float t0 = lce * m;
        v0 += t0;
        v1 += lce - t0;
      }
    } else {
      va = make_float4(1e9f, 1e9f, 1e9f, 1e9f);  // sentinel: forces kernel -> 0
      vb = make_float4(0.f, 0.f, 0.f, 0.f);      // m = 0
    }
    tileA[s] = va; tileB[s] = vb;
  }
  __syncthreads();

  // --- main pair loop: thread owns 2 center rows; half-plane offsets (a>=1), both bins ---
  int txc = tx & 31, ty = tx >> 5;
  int lane = tx & 63;
  int crow = ty*2;
  int cidx = crow*TCOLS + txc + 11;
  Pix c0 = { tileA[cidx],       tileB[cidx] };
  Pix c1 = { tileA[cidx+TCOLS], tileB[cidx+TCOLS] };

  #pragma unroll 1
  for (int bi = 0; bi < 22; ++bi) {
    int db = bi - ((bi < 11) ? 11 : 10);   // -11..-1, 1..11
    int nb = cidx + db;
    float lb = CIND * (float)(db*db);
    Pix N0 = { tileA[nb+TCOLS], tileB[nb+TCOLS] };   // row crow+1
    #pragma unroll
    for (int a = 1; a <= 11; ++a) {
      Pix N1 = { tileA[nb + (a+1)*TCOLS], tileB[nb + (a+1)*TCOLS] };
      float lind = fmaf((float)(a*a), CIND, lb);
      float cc0, cc1;
      {
        float dr = N0.a.x - c0.a.x, dg = N0.a.y - c0.a.y;
        float dbv = N0.a.z - c0.a.z, dd = N0.a.w - c0.a.w;
        float rs = fmaf(dr,dr, fmaf(dg,dg, dbv*dbv));
        float a1 = fmaf(rs, CRGB, lind);
        float a2 = (dd*dd)*CDEP;
        float kv = __builtin_amdgcn_exp2f(a1) + __builtin_amdgcn_exp2f(a2);
        float dt = fmaf(N0.b.x, c0.b.x, fmaf(N0.b.y, c0.b.y, N0.b.z*c0.b.z));
        cc0 = kv * (1.0f - dt);
      }
      {
        float dr = N1.a.x - c1.a.x, dg = N1.a.y - c1.a.y;
        float dbv = N1.a.z - c1.a.z, dd = N1.a.w - c1.a.w;
        float rs = fmaf(dr,dr, fmaf(dg,dg, dbv*dbv));
        float a1 = fmaf(rs, CRGB, lind);
        float a2 = (dd*dd)*CDEP;
        float kv = __builtin_amdgcn_exp2f(a1) + __builtin_amdgcn_exp2f(a2);
        float dt = fmaf(N1.b.x, c1.b.x, fmaf(N1.b.y, c1.b.y, N1.b.z*c1.b.z));
        cc1 = kv * (1.0f - dt);
      }
      float nd = fmaf(cc1, c1.b.w, cc0*c0.b.w);  // -> bin(+a,+db), weighted by center m
      float nr = fmaf(cc1, N1.b.w, cc0*N0.b.w);  // -> bin(-a,-db), weighted by neighbor m
      #pragma unroll
      for (int s = 1; s < 64; s <<= 1) {
        nd += __shfl_xor(nd, s, 64);
        nr += __shfl_xor(nr, s, 64);
      }
      if (lane == 0) {
        atomicAdd(&binsS[(a+SPAN)*KK + (db+SPAN)], nd);
        atomicAdd(&binsS[(SPAN-a)*KK + (SPAN-db)], nr);
      }
      N0 = N1;
    }
  }
  __syncthreads();

  // --- flush bins + CE ---
  for (int s = tx; s < NBINS; s += 256) {
    float v = binsS[s];
    if (v != 0.f) unsafeAtomicAdd(&g_bins[s], v);
  }
  #pragma unroll
  for (int s = 1; s < 64; s <<= 1) {
    v0 += __shfl_xor(v0, s, 64);
    v1 += __shfl_xor(v1, s, 64);
  }
  int wv = tx >> 6;
  if (lane == 0) { redS[wv] = v0; redS[4+wv] = v1; }
  __syncthreads();
  if (tx == 0) {
    unsafeAtomicAdd(&g_ce[0], redS[0]+redS[1]+redS[2]+redS[3]);
    unsafeAtomicAdd(&g_ce[1], redS[4]+redS[5]+redS[6]+redS[7]);
  }
}

// ---------------- fin_kernel: analytic denominators + final combine ----------------
__global__ __launch_bounds__(256) void fin_kernel(const float* __restrict__ g_bins,
                                                  const float* __restrict__ g_ce,
                                                  const float* __restrict__ A,
                                                  float* __restrict__ out) {
  __shared__ float As[23*512];
  __shared__ float Dlo[23*11];
  __shared__ float Dhi[23*12];
  __shared__ float red[8];
  int tx = threadIdx.x;
  for (int s = tx; s < 23*512; s += 256) As[s] = A[s];
  __syncthreads();

  if (tx < 23) {                    // per-dx column prefix of the row-range sums
    int dx = tx - 11;
    int hiIdx = (dx >= 0) ? (22 - dx) : 22;     // row rhi = dx>=0 ? 255-dx : 255
    int loIdx = (dx < 0) ? (-dx - 1) : -1;      // row rlo-1 (only when dx<0)
    const float* hr = &As[hiIdx*512];
    const float* lr = (loIdx >= 0) ? &As[loIdx*512] : nullptr;
    float p = 0.f;
    for (int j = 0; j < 512; ++j) {
      float rr = hr[j] - (lr ? lr[j] : 0.f);
      p += rr;
      if (j < 11)    Dlo[tx*11 + j] = p;
      if (j >= 500)  Dhi[tx*12 + (j-500)] = p;
    }
  }
  __syncthreads();

  float esum = 0.f;
  for (int od = tx; od < NBINS; od += 256) {
    int dxp = od / KK, dyp = od - dxp*KK;
    int dx = dxp - SPAN, dy = dyp - SPAN;
    if (dx != 0 && dy != 0) {
      int chi = 511 - ((dy > 0) ? dy : 0);
      float hi = Dhi[dxp*12 + (chi - 500)];
      float lo = (dy < 0) ? Dlo[dxp*11 + (-dy - 1)] : 0.f;
      esum += g_bins[od] / (hi - lo);
    }
  }
  float csum = 0.f;                               // total sum of dst -> count
  for (int j = tx; j < 512; j += 256) csum += As[22*512 + j];
  #pragma unroll
  for (int s = 1; s < 64; s <<= 1) {
    esum += __shfl_xor(esum, s, 64);
    csum += __shfl_xor(csum, s, 64);
  }
  int lane = tx & 63, wv = tx >> 6;
  if (lane == 0) { red[wv] = esum; red[4+wv] = csum; }
  __syncthreads();
  if (tx == 0) {
    float E = (red[0]+red[1]+red[2]+red[3]) / 529.0f;
    float count = (red[4]+red[5]+red[6]+red[7]) / NPIXF;
    float l1 = g_ce[0] / NPIXF;
    float l2 = g_ce[1] / NPIXF;
    out[0] = l1*(1.0f - count) + l2*count;
    out[1] = E;
  }
}

extern "C" void kernel_launch(void* const* d_in, const int* in_sizes, int n_in,
                              void* d_out, int out_size, void* d_ws, size_t ws_size,
                              hipStream_t stream) {
  const float* logit  = (const float*)d_in[0];
  const int*   target = (const int*)  d_in[1];
  const float* image  = (const float*)d_in[2];
  const float* depth  = (const float*)d_in[3];
  const float* dstm   = (const float*)d_in[4];
  float* out = (float*)d_out;

  float* ws     = (float*)d_ws;
  float* g_bins = ws;            // 529 floats
  float* g_ce   = ws + NBINS;    // 2 floats
  float* A      = ws + 544;      // 23*512 floats

  hipMemsetAsync(ws, 0, 544*sizeof(float), stream);
  den_kernel<<<8, 64, 0, stream>>>(dstm, A);
  crf_kernel<<<dim3(W/TX, H/TYR, 4), 256, 0, stream>>>(logit, target, image, depth, dstm, g_bins, g_ce);
  fin_kernel<<<1, 256, 0, stream>>>(g_bins, g_ce, A, out);
}

// Round 3
// 262.124 us; speedup vs baseline: 3.3438x; 1.7508x over previous
//
#include <hip/hip_runtime.h>

#define H 256
#define W 512
#define HW (H*W)
#define NPIXF 524288.0f
#define SPAN 11
#define KK 23
#define NBINS (KK*KK)   // 529

#define LOG2E 1.4426950408889634f
#define CEXP  (-0.7213475204444817f)   // -0.5*log2(e)
#define CRGB  (CEXP*100.0f)            // 1/SIG_RGB^2
#define CDEP  (CEXP*25.0f)             // 1/SIG_DEPTH^2
#define CIND  (CEXP/36.0f)             // 1/SIG_XY^2

// tile geometry: center 32 cols x 16 rows per block, halo +11 rows below, +-11 cols
#define TX 32
#define TYR 16
#define TROWS 27          // TYR + 11
#define TCOLS 54          // TX + 22
#define TPIX (TROWS*TCOLS) // 1458

struct Pix { float4 a; float4 b; };  // a = (r,g,b,depth), b = (y0,y1,y2,m)

// 64-lane sum on the VALU pipe (DPP). Total lands in lane 63.
__device__ __forceinline__ float dpp_sum(float x) {
  x += __int_as_float(__builtin_amdgcn_update_dpp(0, __float_as_int(x), 0x111, 0xf, 0xf, true)); // row_shr:1
  x += __int_as_float(__builtin_amdgcn_update_dpp(0, __float_as_int(x), 0x112, 0xf, 0xf, true)); // row_shr:2
  x += __int_as_float(__builtin_amdgcn_update_dpp(0, __float_as_int(x), 0x114, 0xf, 0xf, true)); // row_shr:4
  x += __int_as_float(__builtin_amdgcn_update_dpp(0, __float_as_int(x), 0x118, 0xf, 0xf, true)); // row_shr:8
  x += __int_as_float(__builtin_amdgcn_update_dpp(0, __float_as_int(x), 0x142, 0xa, 0xf, true)); // row_bcast:15 -> rows 1,3
  x += __int_as_float(__builtin_amdgcn_update_dpp(0, __float_as_int(x), 0x143, 0xc, 0xf, true)); // row_bcast:31 -> rows 2,3
  return x;
}

__device__ __forceinline__ float wave_sum(float x) {
  #pragma unroll
  for (int s = 1; s < 64; s <<= 1) x += __shfl_xor(x, s, 64);
  return x;
}

// ---------------- stats_kernel: margin band sums of batch-summed dst ----------------
// blocks 0..21: rowBand[k] = sum over row r (r = k<11 ? k : 234+k), all cols, all batches
// blocks 22..43: colBand[k] = sum over col c (c = k<11 ? k : 490+k), all rows, all batches
__global__ __launch_bounds__(256) void stats_kernel(const float* __restrict__ dst,
                                                    float* __restrict__ rowBand,
                                                    float* __restrict__ colBand) {
  int k = blockIdx.x, tx = threadIdx.x;
  float s = 0.f;
  if (k < 22) {
    int row = (k < 11) ? k : (234 + k);
    for (int t = tx; t < 2048; t += 256) {
      int b = t >> 9, j = t & 511;
      s += dst[(size_t)b*HW + row*W + j];
    }
  } else {
    int kc = k - 22;
    int col = (kc < 11) ? kc : (490 + kc);
    for (int t = tx; t < 1024; t += 256) {
      int b = t >> 8, i = t & 255;
      s += dst[(size_t)b*HW + i*W + col];
    }
  }
  s = wave_sum(s);
  __shared__ float r[4];
  if ((tx & 63) == 0) r[tx >> 6] = s;
  __syncthreads();
  if (tx == 0) {
    float tot = r[0] + r[1] + r[2] + r[3];
    if (k < 22) rowBand[k] = tot; else colBand[k - 22] = tot;
  }
}

// ---------------- crf_kernel: LDS-tiled pair loop, DPP reductions, fused softmax/CE ----------------
__global__ __launch_bounds__(256, 3) void crf_kernel(
    const float* __restrict__ logit, const int* __restrict__ target,
    const float* __restrict__ image, const float* __restrict__ depth,
    const float* __restrict__ dst,
    float* __restrict__ g_bins, float* __restrict__ g_ce) {
  __shared__ float4 tileA[TPIX];
  __shared__ float4 tileB[TPIX];
  __shared__ float  binsS[NBINS];
  __shared__ float  redS[12];

  int tx = threadIdx.x;
  int bz = blockIdx.z;
  int i0 = blockIdx.y * TYR;
  int j0 = blockIdx.x * TX;

  const float* lg0 = logit + (size_t)bz*3*HW;
  const float* lg1 = lg0 + HW;
  const float* lg2 = lg0 + 2*HW;
  const float* im0 = image + (size_t)bz*3*HW;
  const float* im1 = im0 + HW;
  const float* im2 = im0 + 2*HW;
  const float* dep = depth + (size_t)bz*HW;
  const float* dsb = dst   + (size_t)bz*HW;
  const int*   tgb = target + (size_t)bz*HW;

  for (int s = tx; s < NBINS; s += 256) binsS[s] = 0.f;

  // --- staging: global -> LDS with fused softmax; fused CE + sum(m) on center pixels ---
  float v0 = 0.f, v1 = 0.f, v2 = 0.f;
  for (int s = tx; s < TPIX; s += 256) {
    int r = s / TCOLS, c = s - r*TCOLS;
    int gi = i0 + r, gj = j0 - 11 + c;
    float4 va, vb;
    if (gi < H && (unsigned)gj < (unsigned)W) {
      int q = gi*W + gj;
      float l0 = lg0[q], l1 = lg1[q], l2 = lg2[q];
      float mx = fmaxf(l0, fmaxf(l1, l2));
      float e0 = __builtin_amdgcn_exp2f((l0-mx)*LOG2E);
      float e1 = __builtin_amdgcn_exp2f((l1-mx)*LOG2E);
      float e2 = __builtin_amdgcn_exp2f((l2-mx)*LOG2E);
      float S = e0+e1+e2;
      float inv = 1.0f/S;
      float m = dsb[q];
      va = make_float4(im0[q], im1[q], im2[q], dep[q]);
      vb = make_float4(e0*inv, e1*inv, e2*inv, m);
      if (r < TYR && c >= 11 && c < 11+TX) {   // center pixel
        int t = tgb[q];
        float lt = (t==0) ? l0 : ((t==1) ? l1 : l2);
        float lce = mx + __logf(S) - lt;
        float t0 = lce * m;
        v0 += t0;
        v1 += lce - t0;
        v2 += m;
      }
    } else {
      va = make_float4(1e9f, 1e9f, 1e9f, 1e9f);  // sentinel: kernel -> exp2(-huge) = 0
      vb = make_float4(0.f, 0.f, 0.f, 0.f);      // m = 0
    }
    tileA[s] = va; tileB[s] = vb;
  }
  __syncthreads();

  // --- main pair loop: thread owns 2 center rows; half-plane offsets (a>=1), both bins ---
  int txc = tx & 31, ty = tx >> 5;
  int lane = tx & 63;
  int crow = ty*2;
  int cidx = crow*TCOLS + txc + 11;
  Pix c0 = { tileA[cidx],       tileB[cidx] };
  Pix c1 = { tileA[cidx+TCOLS], tileB[cidx+TCOLS] };

  #pragma unroll 1
  for (int bi = 0; bi < 22; ++bi) {
    int db = bi - ((bi < 11) ? 11 : 10);   // -11..-1, 1..11
    int nb = cidx + db;
    float lb = CIND * (float)(db*db);
    Pix N0 = { tileA[nb+TCOLS], tileB[nb+TCOLS] };   // row crow+1
    #pragma unroll
    for (int a = 1; a <= 11; ++a) {
      Pix N1 = { tileA[nb + (a+1)*TCOLS], tileB[nb + (a+1)*TCOLS] };
      float lind = fmaf((float)(a*a), CIND, lb);
      float cc0, cc1;
      {
        float dr = N0.a.x - c0.a.x, dg = N0.a.y - c0.a.y;
        float dbv = N0.a.z - c0.a.z, dd = N0.a.w - c0.a.w;
        float rs = fmaf(dr,dr, fmaf(dg,dg, dbv*dbv));
        float a1 = fmaf(rs, CRGB, lind);
        float a2 = (dd*dd)*CDEP;
        float kv = __builtin_amdgcn_exp2f(a1) + __builtin_amdgcn_exp2f(a2);
        float dt = fmaf(N0.b.x, c0.b.x, fmaf(N0.b.y, c0.b.y, N0.b.z*c0.b.z));
        cc0 = kv * (1.0f - dt);
      }
      {
        float dr = N1.a.x - c1.a.x, dg = N1.a.y - c1.a.y;
        float dbv = N1.a.z - c1.a.z, dd = N1.a.w - c1.a.w;
        float rs = fmaf(dr,dr, fmaf(dg,dg, dbv*dbv));
        float a1 = fmaf(rs, CRGB, lind);
        float a2 = (dd*dd)*CDEP;
        float kv = __builtin_amdgcn_exp2f(a1) + __builtin_amdgcn_exp2f(a2);
        float dt = fmaf(N1.b.x, c1.b.x, fmaf(N1.b.y, c1.b.y, N1.b.z*c1.b.z));
        cc1 = kv * (1.0f - dt);
      }
      float nd = fmaf(cc1, c1.b.w, cc0*c0.b.w);  // -> bin(+a,+db), center m
      float nr = fmaf(cc1, N1.b.w, cc0*N0.b.w);  // -> bin(-a,-db), neighbor m
      nd = dpp_sum(nd);
      nr = dpp_sum(nr);
      if (lane == 63) {
        atomicAdd(&binsS[(a+SPAN)*KK + (db+SPAN)], nd);
        atomicAdd(&binsS[(SPAN-a)*KK + (SPAN-db)], nr);
      }
      N0 = N1;
    }
  }
  __syncthreads();

  // --- flush bins + CE ---
  for (int s = tx; s < NBINS; s += 256) {
    float v = binsS[s];
    if (v != 0.f) unsafeAtomicAdd(&g_bins[s], v);
  }
  v0 = dpp_sum(v0); v1 = dpp_sum(v1); v2 = dpp_sum(v2);
  int wv = tx >> 6;
  if (lane == 63) { redS[wv] = v0; redS[4+wv] = v1; redS[8+wv] = v2; }
  __syncthreads();
  if (tx == 0) {
    unsafeAtomicAdd(&g_ce[0], redS[0]+redS[1]+redS[2]+redS[3]);
    unsafeAtomicAdd(&g_ce[1], redS[4]+redS[5]+redS[6]+redS[7]);
    unsafeAtomicAdd(&g_ce[2], redS[8]+redS[9]+redS[10]+redS[11]);
  }
}

// ---------------- fin_kernel: analytic denominators via inclusion-exclusion ----------------
__global__ __launch_bounds__(256) void fin_kernel(const float* __restrict__ g_bins,
                                                  const float* __restrict__ g_ce,
                                                  const float* __restrict__ rowBand,
                                                  const float* __restrict__ colBand,
                                                  const float* __restrict__ dst,
                                                  float* __restrict__ out) {
  __shared__ float corner[22][22];
  __shared__ float rb[22], cb[22];
  __shared__ float TopP[12], BotS[12], LeftP[12], RightS[12];
  __shared__ float TL[12][12], TR[12][12], BL[12][12], BR[12][12];
  __shared__ float red[4];
  int tx = threadIdx.x;
  if (tx < 22) { rb[tx] = rowBand[tx]; cb[tx] = colBand[tx]; }
  for (int t = tx; t < 484; t += 256) {
    int ri = t / 22, ci = t - ri*22;
    int row = (ri < 11) ? ri : (234 + ri);
    int col = (ci < 11) ? ci : (490 + ci);
    float s = 0.f;
    #pragma unroll
    for (int b = 0; b < 4; ++b) s += dst[(size_t)b*HW + row*W + col];
    corner[ri][ci] = s;
  }
  __syncthreads();

  if (tx == 0) { float p=0.f; TopP[0]=0.f;   for (int k=1;k<12;++k){ p += rb[k-1];  TopP[k]=p; } }
  if (tx == 1) { float p=0.f; BotS[0]=0.f;   for (int k=1;k<12;++k){ p += rb[22-k]; BotS[k]=p; } }
  if (tx == 2) { float p=0.f; LeftP[0]=0.f;  for (int k=1;k<12;++k){ p += cb[k-1];  LeftP[k]=p; } }
  if (tx == 3) { float p=0.f; RightS[0]=0.f; for (int k=1;k<12;++k){ p += cb[22-k]; RightS[k]=p; } }
  for (int t = tx; t < 576; t += 256) {
    int tab = t / 144, idx = t - tab*144;
    int a = idx / 12, b = idx - a*12;
    float s = 0.f;
    for (int i = 0; i < a; ++i)
      for (int j = 0; j < b; ++j) {
        int ri = (tab < 2) ? i : (21 - i);
        int ci = (tab & 1) ? (21 - j) : j;
        s += corner[ri][ci];
      }
    if (tab == 0) TL[a][b] = s;
    else if (tab == 1) TR[a][b] = s;
    else if (tab == 2) BL[a][b] = s;
    else BR[a][b] = s;
  }
  __syncthreads();

  float S = g_ce[2];   // sum of dst over everything
  float esum = 0.f;
  for (int od = tx; od < NBINS; od += 256) {
    int dxp = od / KK, dyp = od - dxp*KK;
    int dx = dxp - SPAN, dy = dyp - SPAN;
    if (dx != 0 && dy != 0) {
      int ax = (dx < 0) ? -dx : 0;   // top margin rows excluded
      int bx = (dx > 0) ?  dx : 0;   // bottom margin rows excluded
      int ay = (dy < 0) ? -dy : 0;   // left margin cols excluded
      int by = (dy > 0) ?  dy : 0;   // right margin cols excluded
      float den = S - TopP[ax] - BotS[bx] - LeftP[ay] - RightS[by]
                + TL[ax][ay] + TR[ax][by] + BL[bx][ay] + BR[bx][by];
      esum += g_bins[od] / den;
    }
  }
  esum = wave_sum(esum);
  int lane = tx & 63, wv = tx >> 6;
  if (lane == 0) red[wv] = esum;
  __syncthreads();
  if (tx == 0) {
    float E = (red[0]+red[1]+red[2]+red[3]) / 529.0f;
    float count = S / NPIXF;
    float l1 = g_ce[0] / NPIXF;
    float l2 = g_ce[1] / NPIXF;
    out[0] = l1*(1.0f - count) + l2*count;
    out[1] = E;
  }
}

extern "C" void kernel_launch(void* const* d_in, const int* in_sizes, int n_in,
                              void* d_out, int out_size, void* d_ws, size_t ws_size,
                              hipStream_t stream) {
  const float* logit  = (const float*)d_in[0];
  const int*   target = (const int*)  d_in[1];
  const float* image  = (const float*)d_in[2];
  const float* depth  = (const float*)d_in[3];
  const float* dstm   = (const float*)d_in[4];
  float* out = (float*)d_out;

  float* ws      = (float*)d_ws;
  float* g_bins  = ws;             // 529
  float* g_ce    = ws + NBINS;     // 3  (sum lce*m, sum lce*(1-m), sum m)
  float* rowBand = ws + 532;       // 22
  float* colBand = ws + 554;       // 22

  hipMemsetAsync(ws, 0, 532*sizeof(float), stream);
  stats_kernel<<<44, 256, 0, stream>>>(dstm, rowBand, colBand);
  crf_kernel<<<dim3(W/TX, H/TYR, 4), 256, 0, stream>>>(logit, target, image, depth, dstm, g_bins, g_ce);
  fin_kernel<<<1, 256, 0, stream>>>(g_bins, g_ce, rowBand, colBand, dstm, out);
}

// Round 4
// 259.959 us; speedup vs baseline: 3.3716x; 1.0083x over previous
//
#include <hip/hip_runtime.h>
#include <hip/hip_fp16.h>

#define H 256
#define W 512
#define HW (H*W)
#define NPIXF 524288.0f
#define SPAN 11
#define KK 23
#define NBINS (KK*KK)   // 529

#define LOG2E 1.4426950408889634f
#define CEXP  (-0.7213475204444817f)   // -0.5*log2(e)
#define CRGB  (CEXP*100.0f)            // 1/SIG_RGB^2
#define CDEP  (CEXP*25.0f)             // 1/SIG_DEPTH^2
#define CIND  (CEXP/36.0f)             // 1/SIG_XY^2

// tile geometry: center 32 cols x 16 rows per block, halo +11 rows below, +-11 cols
#define TX 32
#define TYR 16
#define TROWS 27          // TYR + 11
#define TCOLS 54          // TX + 22
#define TPIX (TROWS*TCOLS) // 1458

#define NCRF 1024         // 16x16x4 crf blocks
#define NSTAT 44

struct alignas(16) PixH { __half2 rg, bd, y01, y2m; };   // 16 B staged pixel
struct PF { float r,g,b,d,y0,y1,y2,m; };

__device__ __forceinline__ PF unpackPix(PixH p) {
  PF f;
  f.r = __low2float(p.rg);  f.g = __high2float(p.rg);
  f.b = __low2float(p.bd);  f.d = __high2float(p.bd);
  f.y0 = __low2float(p.y01); f.y1 = __high2float(p.y01);
  f.y2 = __low2float(p.y2m); f.m = __high2float(p.y2m);
  return f;
}

// 64-lane sum on the VALU pipe (DPP). Total lands in lane 63.
__device__ __forceinline__ float dpp_sum(float x) {
  x += __int_as_float(__builtin_amdgcn_update_dpp(0, __float_as_int(x), 0x111, 0xf, 0xf, true)); // row_shr:1
  x += __int_as_float(__builtin_amdgcn_update_dpp(0, __float_as_int(x), 0x112, 0xf, 0xf, true)); // row_shr:2
  x += __int_as_float(__builtin_amdgcn_update_dpp(0, __float_as_int(x), 0x114, 0xf, 0xf, true)); // row_shr:4
  x += __int_as_float(__builtin_amdgcn_update_dpp(0, __float_as_int(x), 0x118, 0xf, 0xf, true)); // row_shr:8
  x += __int_as_float(__builtin_amdgcn_update_dpp(0, __float_as_int(x), 0x142, 0xa, 0xf, true)); // row_bcast:15
  x += __int_as_float(__builtin_amdgcn_update_dpp(0, __float_as_int(x), 0x143, 0xc, 0xf, true)); // row_bcast:31
  return x;
}

__device__ __forceinline__ float wave_sum(float x) {
  #pragma unroll
  for (int s = 1; s < 64; s <<= 1) x += __shfl_xor(x, s, 64);
  return x;
}

// ---------------- crf_kernel: f16 LDS tile, DPP reductions, fused softmax/CE + stats blocks ----------------
__global__ __launch_bounds__(256, 6) void crf_kernel(
    const float* __restrict__ logit, const int* __restrict__ target,
    const float* __restrict__ image, const float* __restrict__ depth,
    const float* __restrict__ dst,
    float* __restrict__ g_bins, float* __restrict__ g_ce,
    float* __restrict__ rowBand, float* __restrict__ colBand) {
  __shared__ PixH  tile[TPIX];
  __shared__ float binsS[NBINS];
  __shared__ float redS[12];

  int tx = threadIdx.x;
  int bid = blockIdx.x;

  if (bid >= NCRF) {           // ---- stats path: margin band sums of dst ----
    int k = bid - NCRF;
    float s = 0.f;
    if (k < 22) {
      int row = (k < 11) ? k : (234 + k);
      for (int t = tx; t < 2048; t += 256) {
        int b = t >> 9, j = t & 511;
        s += dst[(size_t)b*HW + row*W + j];
      }
    } else {
      int kc = k - 22;
      int col = (kc < 11) ? kc : (490 + kc);
      for (int t = tx; t < 1024; t += 256) {
        int b = t >> 8, i = t & 255;
        s += dst[(size_t)b*HW + i*W + col];
      }
    }
    s = wave_sum(s);
    if ((tx & 63) == 0) redS[tx >> 6] = s;
    __syncthreads();
    if (tx == 0) {
      float tot = redS[0] + redS[1] + redS[2] + redS[3];
      if (k < 22) rowBand[k] = tot; else colBand[k - 22] = tot;
    }
    return;
  }

  int bz = bid >> 8;
  int rem = bid & 255;
  int i0 = (rem >> 4) * TYR;
  int j0 = (rem & 15) * TX;

  const float* lg0 = logit + (size_t)bz*3*HW;
  const float* lg1 = lg0 + HW;
  const float* lg2 = lg0 + 2*HW;
  const float* im0 = image + (size_t)bz*3*HW;
  const float* im1 = im0 + HW;
  const float* im2 = im0 + 2*HW;
  const float* dep = depth + (size_t)bz*HW;
  const float* dsb = dst   + (size_t)bz*HW;
  const int*   tgb = target + (size_t)bz*HW;

  for (int s = tx; s < NBINS; s += 256) binsS[s] = 0.f;

  // --- staging: global -> LDS (f16 pack) with fused softmax; fused CE + sum(m) on centers ---
  float v0 = 0.f, v1 = 0.f, v2 = 0.f;
  for (int s = tx; s < TPIX; s += 256) {
    int r = s / TCOLS, c = s - r*TCOLS;
    int gi = i0 + r, gj = j0 - 11 + c;
    PixH ph;
    if (gi < H && (unsigned)gj < (unsigned)W) {
      int q = gi*W + gj;
      float l0 = lg0[q], l1 = lg1[q], l2 = lg2[q];
      float mx = fmaxf(l0, fmaxf(l1, l2));
      float e0 = __builtin_amdgcn_exp2f((l0-mx)*LOG2E);
      float e1 = __builtin_amdgcn_exp2f((l1-mx)*LOG2E);
      float e2 = __builtin_amdgcn_exp2f((l2-mx)*LOG2E);
      float S = e0+e1+e2;
      float inv = 1.0f/S;
      float m = dsb[q];
      ph.rg  = __floats2half2_rn(im0[q], im1[q]);
      ph.bd  = __floats2half2_rn(im2[q], dep[q]);
      ph.y01 = __floats2half2_rn(e0*inv, e1*inv);
      ph.y2m = __floats2half2_rn(e2*inv, m);
      if (r < TYR && c >= 11 && c < 11+TX) {   // center pixel
        int t = tgb[q];
        float lt = (t==0) ? l0 : ((t==1) ? l1 : l2);
        float lce = mx + __logf(S) - lt;
        float t0 = lce * m;
        v0 += t0;
        v1 += lce - t0;
        v2 += m;
      }
    } else {
      ph.rg = ph.bd = __floats2half2_rn(1e30f, 1e30f);  // +inf sentinel -> kernel = 0
      ph.y01 = ph.y2m = __floats2half2_rn(0.f, 0.f);    // m = 0
    }
    tile[s] = ph;
  }
  __syncthreads();

  // --- main pair loop: thread owns 2 center rows; half-plane offsets (a>=1), both bins ---
  int txc = tx & 31, ty = tx >> 5;
  int lane = tx & 63;
  int crow = ty*2;
  int cidx = crow*TCOLS + txc + 11;
  PF c0 = unpackPix(tile[cidx]);
  PF c1 = unpackPix(tile[cidx+TCOLS]);

  #pragma unroll 1
  for (int bi = 0; bi < 22; ++bi) {
    int db = bi - ((bi < 11) ? 11 : 10);   // -11..-1, 1..11
    int nb = cidx + db;
    float lb = CIND * (float)(db*db);
    PF N0 = unpackPix(tile[nb+TCOLS]);     // row crow+1
    #pragma unroll
    for (int a = 1; a <= 11; ++a) {
      PF N1 = unpackPix(tile[nb + (a+1)*TCOLS]);
      float lind = fmaf((float)(a*a), CIND, lb);
      float cc0, cc1;
      {
        float dr = N0.r - c0.r, dg = N0.g - c0.g;
        float dbv = N0.b - c0.b, dd = N0.d - c0.d;
        float rs = fmaf(dr,dr, fmaf(dg,dg, dbv*dbv));
        float a1 = fmaf(rs, CRGB, lind);
        float a2 = (dd*dd)*CDEP;
        float kv = __builtin_amdgcn_exp2f(a1) + __builtin_amdgcn_exp2f(a2);
        float dt = fmaf(N0.y0, c0.y0, fmaf(N0.y1, c0.y1, N0.y2*c0.y2));
        cc0 = kv * (1.0f - dt);
      }
      {
        float dr = N1.r - c1.r, dg = N1.g - c1.g;
        float dbv = N1.b - c1.b, dd = N1.d - c1.d;
        float rs = fmaf(dr,dr, fmaf(dg,dg, dbv*dbv));
        float a1 = fmaf(rs, CRGB, lind);
        float a2 = (dd*dd)*CDEP;
        float kv = __builtin_amdgcn_exp2f(a1) + __builtin_amdgcn_exp2f(a2);
        float dt = fmaf(N1.y0, c1.y0, fmaf(N1.y1, c1.y1, N1.y2*c1.y2));
        cc1 = kv * (1.0f - dt);
      }
      float nd = fmaf(cc1, c1.m, cc0*c0.m);  // -> bin(+a,+db), center m
      float nr = fmaf(cc1, N1.m, cc0*N0.m);  // -> bin(-a,-db), neighbor m
      nd = dpp_sum(nd);
      nr = dpp_sum(nr);
      if (lane == 63) {
        atomicAdd(&binsS[(a+SPAN)*KK + (db+SPAN)], nd);
        atomicAdd(&binsS[(SPAN-a)*KK + (SPAN-db)], nr);
      }
      N0 = N1;
    }
  }
  __syncthreads();

  // --- flush bins + CE ---
  for (int s = tx; s < NBINS; s += 256) {
    float v = binsS[s];
    if (v != 0.f) unsafeAtomicAdd(&g_bins[s], v);
  }
  v0 = dpp_sum(v0); v1 = dpp_sum(v1); v2 = dpp_sum(v2);
  int wv = tx >> 6;
  if (lane == 63) { redS[wv] = v0; redS[4+wv] = v1; redS[8+wv] = v2; }
  __syncthreads();
  if (tx == 0) {
    unsafeAtomicAdd(&g_ce[0], redS[0]+redS[1]+redS[2]+redS[3]);
    unsafeAtomicAdd(&g_ce[1], redS[4]+redS[5]+redS[6]+redS[7]);
    unsafeAtomicAdd(&g_ce[2], redS[8]+redS[9]+redS[10]+redS[11]);
  }
}

// ---------------- fin_kernel: analytic denominators via inclusion-exclusion ----------------
__global__ __launch_bounds__(256) void fin_kernel(const float* __restrict__ g_bins,
                                                  const float* __restrict__ g_ce,
                                                  const float* __restrict__ rowBand,
                                                  const float* __restrict__ colBand,
                                                  const float* __restrict__ dst,
                                                  float* __restrict__ out) {
  __shared__ float corner[22][22];
  __shared__ float rb[22], cb[22];
  __shared__ float TopP[12], BotS[12], LeftP[12], RightS[12];
  __shared__ float TL[12][12], TR[12][12], BL[12][12], BR[12][12];
  __shared__ float red[4];
  int tx = threadIdx.x;
  if (tx < 22) { rb[tx] = rowBand[tx]; cb[tx] = colBand[tx]; }
  for (int t = tx; t < 484; t += 256) {
    int ri = t / 22, ci = t - ri*22;
    int row = (ri < 11) ? ri : (234 + ri);
    int col = (ci < 11) ? ci : (490 + ci);
    float s = 0.f;
    #pragma unroll
    for (int b = 0; b < 4; ++b) s += dst[(size_t)b*HW + row*W + col];
    corner[ri][ci] = s;
  }
  __syncthreads();

  if (tx == 0) { float p=0.f; TopP[0]=0.f;   for (int k=1;k<12;++k){ p += rb[k-1];  TopP[k]=p; } }
  if (tx == 1) { float p=0.f; BotS[0]=0.f;   for (int k=1;k<12;++k){ p += rb[22-k]; BotS[k]=p; } }
  if (tx == 2) { float p=0.f; LeftP[0]=0.f;  for (int k=1;k<12;++k){ p += cb[k-1];  LeftP[k]=p; } }
  if (tx == 3) { float p=0.f; RightS[0]=0.f; for (int k=1;k<12;++k){ p += cb[22-k]; RightS[k]=p; } }
  for (int t = tx; t < 576; t += 256) {
    int tab = t / 144, idx = t - tab*144;
    int a = idx / 12, b = idx - a*12;
    float s = 0.f;
    for (int i = 0; i < a; ++i)
      for (int j = 0; j < b; ++j) {
        int ri = (tab < 2) ? i : (21 - i);
        int ci = (tab & 1) ? (21 - j) : j;
        s += corner[ri][ci];
      }
    if (tab == 0) TL[a][b] = s;
    else if (tab == 1) TR[a][b] = s;
    else if (tab == 2) BL[a][b] = s;
    else BR[a][b] = s;
  }
  __syncthreads();

  float S = g_ce[2];   // sum of dst over everything
  float esum = 0.f;
  for (int od = tx; od < NBINS; od += 256) {
    int dxp = od / KK, dyp = od - dxp*KK;
    int dx = dxp - SPAN, dy = dyp - SPAN;
    if (dx != 0 && dy != 0) {
      int ax = (dx < 0) ? -dx : 0;
      int bx = (dx > 0) ?  dx : 0;
      int ay = (dy < 0) ? -dy : 0;
      int by = (dy > 0) ?  dy : 0;
      float den = S - TopP[ax] - BotS[bx] - LeftP[ay] - RightS[by]
                + TL[ax][ay] + TR[ax][by] + BL[bx][ay] + BR[bx][by];
      esum += g_bins[od] / den;
    }
  }
  esum = wave_sum(esum);
  int lane = tx & 63, wv = tx >> 6;
  if (lane == 0) red[wv] = esum;
  __syncthreads();
  if (tx == 0) {
    float E = (red[0]+red[1]+red[2]+red[3]) / 529.0f;
    float count = S / NPIXF;
    float l1 = g_ce[0] / NPIXF;
    float l2 = g_ce[1] / NPIXF;
    out[0] = l1*(1.0f - count) + l2*count;
    out[1] = E;
  }
}

extern "C" void kernel_launch(void* const* d_in, const int* in_sizes, int n_in,
                              void* d_out, int out_size, void* d_ws, size_t ws_size,
                              hipStream_t stream) {
  const float* logit  = (const float*)d_in[0];
  const int*   target = (const int*)  d_in[1];
  const float* image  = (const float*)d_in[2];
  const float* depth  = (const float*)d_in[3];
  const float* dstm   = (const float*)d_in[4];
  float* out = (float*)d_out;

  float* ws      = (float*)d_ws;
  float* g_bins  = ws;             // 529
  float* g_ce    = ws + NBINS;     // 3  (sum lce*m, sum lce*(1-m), sum m)
  float* rowBand = ws + 532;       // 22
  float* colBand = ws + 554;       // 22

  hipMemsetAsync(ws, 0, 532*sizeof(float), stream);
  crf_kernel<<<NCRF + NSTAT, 256, 0, stream>>>(logit, target, image, depth, dstm,
                                               g_bins, g_ce, rowBand, colBand);
  fin_kernel<<<1, 256, 0, stream>>>(g_bins, g_ce, rowBand, colBand, dstm, out);
}